// Round 5
// baseline (1252.243 us; speedup 1.0000x reference)
//
#include <hip/hip_runtime.h>

#define NH 4     // heads
#define CH 64    // channels/head

__device__ __forceinline__ unsigned short f2bf(float f) {  // round-to-nearest-even
  unsigned b = __float_as_uint(f);
  return (unsigned short)((b + 0x7fffu + ((b >> 16) & 1u)) >> 16);
}

// ---------------- encoder: h = relu(x @ W + b); x:[N,8], W:[8,64] ----------------
__global__ void encoder_kernel(const float* __restrict__ x, const float* __restrict__ W,
                               const float* __restrict__ b, float* __restrict__ h, int N) {
  int idx = blockIdx.x * blockDim.x + threadIdx.x;
  if (idx >= N * 64) return;
  int n = idx >> 6, j = idx & 63;
  const float* xp = x + n * 8;
  float acc = b[j];
#pragma unroll
  for (int k = 0; k < 8; ++k) acc = fmaf(xp[k], W[k * 64 + j], acc);
  h[idx] = fmaxf(acc, 0.0f);
}

// ------- xl(bf16) = h@Wl + bl, xr(fp32) = h@Wr + br; h:[N,K], W:[K,256] -------
template <int K>
__global__ void lin_lr_kernel(const float* __restrict__ h,
                              const float* __restrict__ Wl, const float* __restrict__ bl,
                              const float* __restrict__ Wr, const float* __restrict__ br,
                              unsigned short* __restrict__ xlb, float* __restrict__ xr, int N) {
  __shared__ float hs[8][K];
  int n0 = blockIdx.x * 8;
  int j = threadIdx.x;  // output column
  int nmax = N - n0; if (nmax > 8) nmax = 8;
  for (int idx = j; idx < nmax * K; idx += 256) {
    int m = idx / K, k = idx % K;
    hs[m][k] = h[(size_t)(n0 + m) * K + k];
  }
  __syncthreads();
  float accl[8], accr[8];
  float bjl = bl[j], bjr = br[j];
#pragma unroll
  for (int m = 0; m < 8; ++m) { accl[m] = bjl; accr[m] = bjr; }
  for (int k = 0; k < K; ++k) {
    float wl = Wl[k * 256 + j];
    float wr = Wr[k * 256 + j];
#pragma unroll
    for (int m = 0; m < 8; ++m) {
      accl[m] = fmaf(hs[m][k], wl, accl[m]);
      accr[m] = fmaf(hs[m][k], wr, accr[m]);
    }
  }
  for (int m = 0; m < nmax; ++m) {
    xlb[(size_t)(n0 + m) * 256 + j] = f2bf(accl[m]);
    xr[(size_t)(n0 + m) * 256 + j] = accr[m];
  }
}

// ---------------- CSR build (counting sort by dst), fully parallel scan ----------------
__global__ void hist_kernel(const int* __restrict__ dst, int* __restrict__ deg, int E) {
  int e = blockIdx.x * blockDim.x + threadIdx.x;
  if (e < E) atomicAdd(&deg[dst[e]], 1);
}

__global__ void scan_partial_kernel(const int* __restrict__ deg, int* __restrict__ partial, int N) {
  __shared__ int sm[256];
  int t = threadIdx.x;
  int i = blockIdx.x * 256 + t;
  sm[t] = (i < N) ? deg[i] : 0;
  __syncthreads();
#pragma unroll
  for (int s = 128; s > 0; s >>= 1) {
    if (t < s) sm[t] += sm[t + s];
    __syncthreads();
  }
  if (t == 0) partial[blockIdx.x] = sm[0];
}

__global__ void scan_offsets_kernel(int* __restrict__ partial, int nb) {
  __shared__ int sm[256];
  int t = threadIdx.x;
  int v = (t < nb) ? partial[t] : 0;
  sm[t] = v;
  __syncthreads();
#pragma unroll
  for (int off = 1; off < 256; off <<= 1) {
    int a = (t >= off) ? sm[t - off] : 0;
    __syncthreads();
    sm[t] += a;
    __syncthreads();
  }
  if (t < nb) partial[t] = sm[t] - v;  // exclusive
}

__global__ void scan_final_kernel(const int* __restrict__ deg, const int* __restrict__ partial,
                                  int* __restrict__ rowptr, int* __restrict__ cursor, int N, int E) {
  __shared__ int sm[256];
  int t = threadIdx.x;
  int i = blockIdx.x * 256 + t;
  int v = (i < N) ? deg[i] : 0;
  sm[t] = v;
  __syncthreads();
#pragma unroll
  for (int off = 1; off < 256; off <<= 1) {
    int a = (t >= off) ? sm[t - off] : 0;
    __syncthreads();
    sm[t] += a;
    __syncthreads();
  }
  if (i < N) {
    int ex = partial[blockIdx.x] + sm[t] - v;
    rowptr[i] = ex;
    cursor[i] = ex;
  }
  if (i == 0) rowptr[N] = E;
}

// edges packed as (src, ea_bits) for a single dwordx2 per edge
__global__ void scatter_build_kernel(const int* __restrict__ src, const int* __restrict__ dst,
                                     const float* __restrict__ ea, int* __restrict__ cursor,
                                     int2* __restrict__ edg, int E) {
  int e = blockIdx.x * blockDim.x + threadIdx.x;
  if (e >= E) return;
  int d = dst[e];
  int pos = atomicAdd(&cursor[d], 1);
  edg[pos] = make_int2(src[e], __float_as_int(ea[e]));
}

// ---------------- fused GATv2 aggregate, 2-edges-per-gather-instruction ----------------
// One wave per node. Lanes split in two halves; each half processes its own edge
// stream. Within a half, sub-lane sl (0..31) owns 8 consecutive channels
// [8sl, 8sl+8) (head = sl>>3), loaded as one uint4 (8 bf16). A single wave64
// gather instruction thus fetches TWO edges' 512B rows.
__device__ __forceinline__ void edge_accum8(const uint4 q, const float eav,
                                            const float* xr8, const float* We8, const float* at8,
                                            float* acc, float& denom) {
  float xl[8];
  xl[0] = __uint_as_float(q.x << 16); xl[1] = __uint_as_float(q.x & 0xffff0000u);
  xl[2] = __uint_as_float(q.y << 16); xl[3] = __uint_as_float(q.y & 0xffff0000u);
  xl[4] = __uint_as_float(q.z << 16); xl[5] = __uint_as_float(q.z & 0xffff0000u);
  xl[6] = __uint_as_float(q.w << 16); xl[7] = __uint_as_float(q.w & 0xffff0000u);
  float p = 0.f;
#pragma unroll
  for (int k = 0; k < 8; ++k) {
    float v = fmaf(eav, We8[k], xl[k] + xr8[k]);
    v = (v >= 0.f) ? v : 0.2f * v;            // leaky_relu(0.2)
    p = fmaf(v, at8[k], p);
  }
  p += __shfl_xor(p, 1, 64);
  p += __shfl_xor(p, 2, 64);
  p += __shfl_xor(p, 4, 64);                  // 8-lane head group (stays in half)
  float ex = __expf(p);
  denom += ex;
#pragma unroll
  for (int k = 0; k < 8; ++k) acc[k] = fmaf(ex, xl[k], acc[k]);
}

template <bool POOL>
__global__ void gat_aggregate_kernel(const int* __restrict__ rowptr,
                                     const int2* __restrict__ edg,
                                     const unsigned short* __restrict__ xlb,
                                     const float* __restrict__ xr,
                                     const float* __restrict__ We,
                                     const float* __restrict__ att,
                                     const float* __restrict__ bias,
                                     float* __restrict__ out,
                                     const int* __restrict__ batch,
                                     float* __restrict__ sums,
                                     float* __restrict__ cnt,
                                     int N) {
  int d = (int)((blockIdx.x * (size_t)blockDim.x + threadIdx.x) >> 6);
  int lane = threadIdx.x & 63;
  if (d >= N) return;
  int half = lane >> 5;        // 0 or 1: which edge of the pair
  int sl = lane & 31;          // sub-lane within the edge
  int c0 = sl * 8;             // first of this lane's 8 channels

  const uint4* xlp = (const uint4*)xlb;   // row = 32 uint4
  float xr8[8], We8[8], at8[8];
  {
    float4 a = *(const float4*)(xr + (size_t)d * 256 + c0);
    float4 b = *(const float4*)(xr + (size_t)d * 256 + c0 + 4);
    xr8[0]=a.x; xr8[1]=a.y; xr8[2]=a.z; xr8[3]=a.w; xr8[4]=b.x; xr8[5]=b.y; xr8[6]=b.z; xr8[7]=b.w;
    a = *(const float4*)(We + c0); b = *(const float4*)(We + c0 + 4);
    We8[0]=a.x; We8[1]=a.y; We8[2]=a.z; We8[3]=a.w; We8[4]=b.x; We8[5]=b.y; We8[6]=b.z; We8[7]=b.w;
    a = *(const float4*)(att + c0); b = *(const float4*)(att + c0 + 4);
    at8[0]=a.x; at8[1]=a.y; at8[2]=a.z; at8[3]=a.w; at8[4]=b.x; at8[5]=b.y; at8[6]=b.z; at8[7]=b.w;
  }
  int beg = rowptr[d], end = rowptr[d + 1];
  float acc[8] = {0.f,0.f,0.f,0.f,0.f,0.f,0.f,0.f};
  float denom = 0.f;
  int i = beg;
  for (; i + 3 < end; i += 4) {           // 4 edges in flight (2 per half)
    int2 ea_ = edg[i + half];
    int2 eb_ = edg[i + 2 + half];
    uint4 qa = xlp[(size_t)ea_.x * 32 + sl];
    uint4 qb = xlp[(size_t)eb_.x * 32 + sl];
    edge_accum8(qa, __int_as_float(ea_.y), xr8, We8, at8, acc, denom);
    edge_accum8(qb, __int_as_float(eb_.y), xr8, We8, at8, acc, denom);
  }
  for (; i + 1 < end; i += 2) {           // pair
    int2 ea_ = edg[i + half];
    uint4 qa = xlp[(size_t)ea_.x * 32 + sl];
    edge_accum8(qa, __int_as_float(ea_.y), xr8, We8, at8, acc, denom);
  }
  if (i < end && half == 0) {             // last single edge: half 0 only
    int2 ea_ = edg[i];
    uint4 qa = xlp[(size_t)ea_.x * 32 + sl];
    edge_accum8(qa, __int_as_float(ea_.y), xr8, We8, at8, acc, denom);
  }
  // combine the two halves (channel sets are identical across halves)
  denom += __shfl_xor(denom, 32, 64);
#pragma unroll
  for (int k = 0; k < 8; ++k) acc[k] += __shfl_xor(acc[k], 32, 64);
  float inv = 1.f / (denom + 1e-16f);
  if (half == 0) {
    float4 b0 = *(const float4*)(bias + c0);
    float4 b1 = *(const float4*)(bias + c0 + 4);
    float o[8];
    o[0] = fmaxf(fmaf(acc[0], inv, b0.x), 0.f);
    o[1] = fmaxf(fmaf(acc[1], inv, b0.y), 0.f);
    o[2] = fmaxf(fmaf(acc[2], inv, b0.z), 0.f);
    o[3] = fmaxf(fmaf(acc[3], inv, b0.w), 0.f);
    o[4] = fmaxf(fmaf(acc[4], inv, b1.x), 0.f);
    o[5] = fmaxf(fmaf(acc[5], inv, b1.y), 0.f);
    o[6] = fmaxf(fmaf(acc[6], inv, b1.z), 0.f);
    o[7] = fmaxf(fmaf(acc[7], inv, b1.w), 0.f);
    if (POOL) {
      int g = batch[d];
      float* sg = sums + (size_t)g * 256 + c0;
#pragma unroll
      for (int k = 0; k < 8; ++k) atomicAdd(sg + k, o[k]);
      if (sl == 0) atomicAdd(&cnt[g], 1.0f);
    } else {
      float* op = out + (size_t)d * 256 + c0;
      *(float4*)op = make_float4(o[0], o[1], o[2], o[3]);
      *(float4*)(op + 4) = make_float4(o[4], o[5], o[6], o[7]);
    }
  }
}

// ---------------- per-graph MLP head ----------------
__global__ void mlp_kernel(const float* __restrict__ sums, const float* __restrict__ cnt,
                           const float* __restrict__ p1W, const float* __restrict__ p1b,
                           const float* __restrict__ lng, const float* __restrict__ lnb,
                           const float* __restrict__ p2W, const float* __restrict__ p2b,
                           float* __restrict__ outp, int G) {
  __shared__ float p[256];
  __shared__ float z[128];
  __shared__ float wsum[2];
  __shared__ float wsum2[2];
  int g = blockIdx.x;
  int t = threadIdx.x;  // 0..127
  float c = fmaxf(cnt[g], 1.0f);
  p[t] = sums[(size_t)g * 256 + t] / c;
  p[t + 128] = sums[(size_t)g * 256 + t + 128] / c;
  __syncthreads();
  float acc = p1b[t];
  for (int k = 0; k < 256; ++k) acc = fmaf(p[k], p1W[k * 128 + t], acc);
  float v = acc;
#pragma unroll
  for (int off = 32; off > 0; off >>= 1) v += __shfl_xor(v, off, 64);
  if ((t & 63) == 0) wsum[t >> 6] = v;
  __syncthreads();
  float mu = (wsum[0] + wsum[1]) * (1.0f / 128.0f);
  float dv = acc - mu;
  float vv = dv * dv;
#pragma unroll
  for (int off = 32; off > 0; off >>= 1) vv += __shfl_xor(vv, off, 64);
  if ((t & 63) == 0) wsum2[t >> 6] = vv;
  __syncthreads();
  float var = (wsum2[0] + wsum2[1]) * (1.0f / 128.0f);
  float zv = dv * rsqrtf(var + 1e-5f) * lng[t] + lnb[t];
  z[t] = fmaxf(zv, 0.0f);
  __syncthreads();
  if (t < 64) {
    float o = p2b[t];
    for (int k = 0; k < 128; ++k) o = fmaf(z[k], p2W[k * 64 + t], o);
    outp[(size_t)g * 64 + t] = fmaxf(o, 0.0f);
  }
}

extern "C" void kernel_launch(void* const* d_in, const int* in_sizes, int n_in,
                              void* d_out, int out_size, void* d_ws, size_t ws_size,
                              hipStream_t stream) {
  const float* x      = (const float*)d_in[0];
  const int*   ei     = (const int*)d_in[1];
  const float* ea     = (const float*)d_in[2];
  const int*   batch  = (const int*)d_in[3];
  const float* enc_W  = (const float*)d_in[4];
  const float* enc_b  = (const float*)d_in[5];
  const float* Wl1    = (const float*)d_in[6];
  const float* bl1    = (const float*)d_in[7];
  const float* Wr1    = (const float*)d_in[8];
  const float* br1    = (const float*)d_in[9];
  const float* We1    = (const float*)d_in[10];
  const float* att1   = (const float*)d_in[11];
  const float* bias1  = (const float*)d_in[12];
  const float* Wl2    = (const float*)d_in[13];
  const float* bl2    = (const float*)d_in[14];
  const float* Wr2    = (const float*)d_in[15];
  const float* br2    = (const float*)d_in[16];
  const float* We2    = (const float*)d_in[17];
  const float* att2   = (const float*)d_in[18];
  const float* bias2  = (const float*)d_in[19];
  const float* p1W    = (const float*)d_in[20];
  const float* p1b    = (const float*)d_in[21];
  const float* lng    = (const float*)d_in[22];
  const float* lnb    = (const float*)d_in[23];
  const float* p2W    = (const float*)d_in[24];
  const float* p2b    = (const float*)d_in[25];
  float* outp = (float*)d_out;

  int N = in_sizes[0] / 8;
  int E = in_sizes[2];
  int G = out_size / 64;
  const int* src = ei;
  const int* dst = ei + E;
  int nb = (N + 255) / 256;   // <=256 scan blocks (N=50000 -> 196)

  // workspace layout
  float* ws      = (float*)d_ws;
  float* h0      = ws;                          // N*64 f32
  float* B1      = h0     + (size_t)N * 64;     // N*256 f32 (xr)
  float* B2      = B1     + (size_t)N * 256;    // N*256 f32 (layer1 out)
  float* sums    = B2     + (size_t)N * 256;    // G*256
  float* cnt     = sums   + (size_t)G * 256;    // G
  unsigned short* xlb = (unsigned short*)(cnt + G);      // N*256 bf16 (16B-aligned)
  int2*  edg     = (int2*)(xlb + (size_t)N * 256);       // E (src, ea)
  int*   rowptr  = (int*)(edg + (size_t)E);              // N+1
  int*   cursor  = rowptr + (size_t)(N + 1);             // N
  int*   partial = cursor + (size_t)N;                   // nb

  // encoder
  encoder_kernel<<<(N * 64 + 255) / 256, 256, 0, stream>>>(x, enc_W, enc_b, h0, N);

  // CSR build (shared by both layers — dst is static)
  hipMemsetAsync(cursor, 0, (size_t)N * sizeof(int), stream);
  hist_kernel<<<(E + 255) / 256, 256, 0, stream>>>(dst, cursor, E);
  scan_partial_kernel<<<nb, 256, 0, stream>>>(cursor, partial, N);
  scan_offsets_kernel<<<1, 256, 0, stream>>>(partial, nb);
  scan_final_kernel<<<nb, 256, 0, stream>>>(cursor, partial, rowptr, cursor, N, E);
  scatter_build_kernel<<<(E + 255) / 256, 256, 0, stream>>>(src, dst, ea, cursor, edg, E);

  // GAT layer 1 (K=64): h0 -> B2
  lin_lr_kernel<64><<<(N + 7) / 8, 256, 0, stream>>>(h0, Wl1, bl1, Wr1, br1, xlb, B1, N);
  gat_aggregate_kernel<false><<<(N + 3) / 4, 256, 0, stream>>>(
      rowptr, edg, xlb, B1, We1, att1, bias1, B2, nullptr, nullptr, nullptr, N);

  // GAT layer 2 (K=256): B2 -> pooled sums directly
  lin_lr_kernel<256><<<(N + 7) / 8, 256, 0, stream>>>(B2, Wl2, bl2, Wr2, br2, xlb, B1, N);
  hipMemsetAsync(sums, 0, ((size_t)G * 256 + G) * sizeof(float), stream);
  gat_aggregate_kernel<true><<<(N + 3) / 4, 256, 0, stream>>>(
      rowptr, edg, xlb, B1, We2, att2, bias2, nullptr, batch, sums, cnt, N);

  // per-graph MLP
  mlp_kernel<<<G, 128, 0, stream>>>(sums, cnt, p1W, p1b, lng, lnb, p2W, p2b, outp, G);
}

// Round 6
// 1042.766 us; speedup vs baseline: 1.2009x; 1.2009x over previous
//
#include <hip/hip_runtime.h>

#define NH 4     // heads
#define CH 64    // channels/head

__device__ __forceinline__ unsigned short f2bf(float f) {  // round-to-nearest-even
  unsigned b = __float_as_uint(f);
  return (unsigned short)((b + 0x7fffu + ((b >> 16) & 1u)) >> 16);
}
__device__ __forceinline__ float bf2f(unsigned short u) {
  return __uint_as_float(((unsigned)u) << 16);
}

// ---------------- encoder: h = relu(x @ W + b); x:[N,8], W:[8,64] ----------------
__global__ void encoder_kernel(const float* __restrict__ x, const float* __restrict__ W,
                               const float* __restrict__ b, float* __restrict__ h, int N) {
  int idx = blockIdx.x * blockDim.x + threadIdx.x;
  if (idx >= N * 64) return;
  int n = idx >> 6, j = idx & 63;
  const float* xp = x + n * 8;
  float acc = b[j];
#pragma unroll
  for (int k = 0; k < 8; ++k) acc = fmaf(xp[k], W[k * 64 + j], acc);
  h[idx] = fmaxf(acc, 0.0f);
}

// ------- xl(bf16) = h@Wl + bl, xr(fp32) = h@Wr + br; h:[N,K], W:[K,256] -------
template <int K>
__global__ void lin_lr_kernel(const float* __restrict__ h,
                              const float* __restrict__ Wl, const float* __restrict__ bl,
                              const float* __restrict__ Wr, const float* __restrict__ br,
                              unsigned short* __restrict__ xlb, float* __restrict__ xr, int N) {
  __shared__ float hs[8][K];
  int n0 = blockIdx.x * 8;
  int j = threadIdx.x;  // output column
  int nmax = N - n0; if (nmax > 8) nmax = 8;
  for (int idx = j; idx < nmax * K; idx += 256) {
    int m = idx / K, k = idx % K;
    hs[m][k] = h[(size_t)(n0 + m) * K + k];
  }
  __syncthreads();
  float accl[8], accr[8];
  float bjl = bl[j], bjr = br[j];
#pragma unroll
  for (int m = 0; m < 8; ++m) { accl[m] = bjl; accr[m] = bjr; }
  for (int k = 0; k < K; ++k) {
    float wl = Wl[k * 256 + j];
    float wr = Wr[k * 256 + j];
#pragma unroll
    for (int m = 0; m < 8; ++m) {
      accl[m] = fmaf(hs[m][k], wl, accl[m]);
      accr[m] = fmaf(hs[m][k], wr, accr[m]);
    }
  }
  for (int m = 0; m < nmax; ++m) {
    xlb[(size_t)(n0 + m) * 256 + j] = f2bf(accl[m]);
    xr[(size_t)(n0 + m) * 256 + j] = accr[m];
  }
}

// ---------------- CSR build (counting sort by dst), fully parallel scan ----------------
__global__ void hist_kernel(const int* __restrict__ dst, int* __restrict__ deg, int E) {
  int e = blockIdx.x * blockDim.x + threadIdx.x;
  if (e < E) atomicAdd(&deg[dst[e]], 1);
}

__global__ void scan_partial_kernel(const int* __restrict__ deg, int* __restrict__ partial, int N) {
  __shared__ int sm[256];
  int t = threadIdx.x;
  int i = blockIdx.x * 256 + t;
  sm[t] = (i < N) ? deg[i] : 0;
  __syncthreads();
#pragma unroll
  for (int s = 128; s > 0; s >>= 1) {
    if (t < s) sm[t] += sm[t + s];
    __syncthreads();
  }
  if (t == 0) partial[blockIdx.x] = sm[0];
}

__global__ void scan_offsets_kernel(int* __restrict__ partial, int nb) {
  __shared__ int sm[256];
  int t = threadIdx.x;
  int v = (t < nb) ? partial[t] : 0;
  sm[t] = v;
  __syncthreads();
#pragma unroll
  for (int off = 1; off < 256; off <<= 1) {
    int a = (t >= off) ? sm[t - off] : 0;
    __syncthreads();
    sm[t] += a;
    __syncthreads();
  }
  if (t < nb) partial[t] = sm[t] - v;  // exclusive
}

__global__ void scan_final_kernel(const int* __restrict__ deg, const int* __restrict__ partial,
                                  int* __restrict__ rowptr, int* __restrict__ cursor, int N, int E) {
  __shared__ int sm[256];
  int t = threadIdx.x;
  int i = blockIdx.x * 256 + t;
  int v = (i < N) ? deg[i] : 0;
  sm[t] = v;
  __syncthreads();
#pragma unroll
  for (int off = 1; off < 256; off <<= 1) {
    int a = (t >= off) ? sm[t - off] : 0;
    __syncthreads();
    sm[t] += a;
    __syncthreads();
  }
  if (i < N) {
    int ex = partial[blockIdx.x] + sm[t] - v;
    rowptr[i] = ex;
    cursor[i] = ex;
  }
  if (i == 0) rowptr[N] = E;
}

// edges packed as (src, ea_bits) for a single dwordx2 per edge
__global__ void scatter_build_kernel(const int* __restrict__ src, const int* __restrict__ dst,
                                     const float* __restrict__ ea, int* __restrict__ cursor,
                                     int2* __restrict__ edg, int E) {
  int e = blockIdx.x * blockDim.x + threadIdx.x;
  if (e >= E) return;
  int d = dst[e];
  int pos = atomicAdd(&cursor[d], 1);
  edg[pos] = make_int2(src[e], __float_as_int(ea[e]));
}

// ---------------- fused GATv2: alpha + softmax + aggregate + bias + relu ----------------
// One wave per node (R2 structure). Lane l owns channels 4l..4l+3 (head = l>>4).
// One full-wave ushort4 gather (64 x 8B = full 512B bf16 row) per edge.
__device__ __forceinline__ void edge_accum(const ushort4 xu, const float eav,
                                           const float4 xr4, const float4 We4, const float4 at4,
                                           float4& acc, float& denom) {
  float4 xlv;
  xlv.x = bf2f(xu.x); xlv.y = bf2f(xu.y); xlv.z = bf2f(xu.z); xlv.w = bf2f(xu.w);
  float4 v;
  v.x = fmaf(eav, We4.x, xlv.x + xr4.x);
  v.y = fmaf(eav, We4.y, xlv.y + xr4.y);
  v.z = fmaf(eav, We4.z, xlv.z + xr4.z);
  v.w = fmaf(eav, We4.w, xlv.w + xr4.w);
  v.x = (v.x >= 0.f) ? v.x : 0.2f * v.x;
  v.y = (v.y >= 0.f) ? v.y : 0.2f * v.y;
  v.z = (v.z >= 0.f) ? v.z : 0.2f * v.z;
  v.w = (v.w >= 0.f) ? v.w : 0.2f * v.w;
  float p = v.x * at4.x + v.y * at4.y + v.z * at4.z + v.w * at4.w;
  p += __shfl_xor(p, 1, 64);
  p += __shfl_xor(p, 2, 64);
  p += __shfl_xor(p, 4, 64);
  p += __shfl_xor(p, 8, 64);   // all 16 lanes of the head group hold alpha_h
  float ex = __expf(p);
  denom += ex;
  acc.x = fmaf(ex, xlv.x, acc.x);
  acc.y = fmaf(ex, xlv.y, acc.y);
  acc.z = fmaf(ex, xlv.z, acc.z);
  acc.w = fmaf(ex, xlv.w, acc.w);
}

template <bool POOL>
__global__ void gat_aggregate_kernel(const int* __restrict__ rowptr,
                                     const int2* __restrict__ edg,
                                     const unsigned short* __restrict__ xlb,
                                     const float* __restrict__ xr,
                                     const float* __restrict__ We,
                                     const float* __restrict__ att,
                                     const float* __restrict__ bias,
                                     float* __restrict__ out,
                                     const int* __restrict__ batch,
                                     float* __restrict__ sums,
                                     float* __restrict__ cnt,
                                     int N) {
  int d = (int)((blockIdx.x * (size_t)blockDim.x + threadIdx.x) >> 6);
  int lane = threadIdx.x & 63;
  if (d >= N) return;
  const ushort4* xlp = (const ushort4*)xlb;   // row = 64 ushort4
  float4 xr4 = ((const float4*)xr)[(size_t)d * 64 + lane];
  float4 We4 = ((const float4*)We)[lane];
  float4 at4 = ((const float4*)att)[lane];
  int beg = rowptr[d], end = rowptr[d + 1];
  float4 acc = {0.f, 0.f, 0.f, 0.f};
  float denom = 0.f;
  int i = beg;
  for (; i + 1 < end; i += 2) {     // 2 gathers in flight (R2's winning depth)
    int2 e0 = edg[i], e1 = edg[i + 1];
    ushort4 a0 = xlp[(size_t)e0.x * 64 + lane];
    ushort4 a1 = xlp[(size_t)e1.x * 64 + lane];
    edge_accum(a0, __int_as_float(e0.y), xr4, We4, at4, acc, denom);
    edge_accum(a1, __int_as_float(e1.y), xr4, We4, at4, acc, denom);
  }
  if (i < end) {
    int2 e0 = edg[i];
    ushort4 a0 = xlp[(size_t)e0.x * 64 + lane];
    edge_accum(a0, __int_as_float(e0.y), xr4, We4, at4, acc, denom);
  }
  float inv = 1.f / (denom + 1e-16f);
  float4 b4 = ((const float4*)bias)[lane];
  float4 o;
  o.x = fmaxf(fmaf(acc.x, inv, b4.x), 0.f);
  o.y = fmaxf(fmaf(acc.y, inv, b4.y), 0.f);
  o.z = fmaxf(fmaf(acc.z, inv, b4.z), 0.f);
  o.w = fmaxf(fmaf(acc.w, inv, b4.w), 0.f);
  if (POOL) {
    int g = batch[d];
    float* sg = sums + (size_t)g * 256 + lane * 4;
    atomicAdd(sg + 0, o.x);
    atomicAdd(sg + 1, o.y);
    atomicAdd(sg + 2, o.z);
    atomicAdd(sg + 3, o.w);
    if (lane == 0) atomicAdd(&cnt[g], 1.0f);
  } else {
    ((float4*)out)[(size_t)d * 64 + lane] = o;
  }
}

// ---------------- per-graph MLP head ----------------
__global__ void mlp_kernel(const float* __restrict__ sums, const float* __restrict__ cnt,
                           const float* __restrict__ p1W, const float* __restrict__ p1b,
                           const float* __restrict__ lng, const float* __restrict__ lnb,
                           const float* __restrict__ p2W, const float* __restrict__ p2b,
                           float* __restrict__ outp, int G) {
  __shared__ float p[256];
  __shared__ float z[128];
  __shared__ float wsum[2];
  __shared__ float wsum2[2];
  int g = blockIdx.x;
  int t = threadIdx.x;  // 0..127
  float c = fmaxf(cnt[g], 1.0f);
  p[t] = sums[(size_t)g * 256 + t] / c;
  p[t + 128] = sums[(size_t)g * 256 + t + 128] / c;
  __syncthreads();
  float acc = p1b[t];
  for (int k = 0; k < 256; ++k) acc = fmaf(p[k], p1W[k * 128 + t], acc);
  float v = acc;
#pragma unroll
  for (int off = 32; off > 0; off >>= 1) v += __shfl_xor(v, off, 64);
  if ((t & 63) == 0) wsum[t >> 6] = v;
  __syncthreads();
  float mu = (wsum[0] + wsum[1]) * (1.0f / 128.0f);
  float dv = acc - mu;
  float vv = dv * dv;
#pragma unroll
  for (int off = 32; off > 0; off >>= 1) vv += __shfl_xor(vv, off, 64);
  if ((t & 63) == 0) wsum2[t >> 6] = vv;
  __syncthreads();
  float var = (wsum2[0] + wsum2[1]) * (1.0f / 128.0f);
  float zv = dv * rsqrtf(var + 1e-5f) * lng[t] + lnb[t];
  z[t] = fmaxf(zv, 0.0f);
  __syncthreads();
  if (t < 64) {
    float o = p2b[t];
    for (int k = 0; k < 128; ++k) o = fmaf(z[k], p2W[k * 64 + t], o);
    outp[(size_t)g * 64 + t] = fmaxf(o, 0.0f);
  }
}

extern "C" void kernel_launch(void* const* d_in, const int* in_sizes, int n_in,
                              void* d_out, int out_size, void* d_ws, size_t ws_size,
                              hipStream_t stream) {
  const float* x      = (const float*)d_in[0];
  const int*   ei     = (const int*)d_in[1];
  const float* ea     = (const float*)d_in[2];
  const int*   batch  = (const int*)d_in[3];
  const float* enc_W  = (const float*)d_in[4];
  const float* enc_b  = (const float*)d_in[5];
  const float* Wl1    = (const float*)d_in[6];
  const float* bl1    = (const float*)d_in[7];
  const float* Wr1    = (const float*)d_in[8];
  const float* br1    = (const float*)d_in[9];
  const float* We1    = (const float*)d_in[10];
  const float* att1   = (const float*)d_in[11];
  const float* bias1  = (const float*)d_in[12];
  const float* Wl2    = (const float*)d_in[13];
  const float* bl2    = (const float*)d_in[14];
  const float* Wr2    = (const float*)d_in[15];
  const float* br2    = (const float*)d_in[16];
  const float* We2    = (const float*)d_in[17];
  const float* att2   = (const float*)d_in[18];
  const float* bias2  = (const float*)d_in[19];
  const float* p1W    = (const float*)d_in[20];
  const float* p1b    = (const float*)d_in[21];
  const float* lng    = (const float*)d_in[22];
  const float* lnb    = (const float*)d_in[23];
  const float* p2W    = (const float*)d_in[24];
  const float* p2b    = (const float*)d_in[25];
  float* outp = (float*)d_out;

  int N = in_sizes[0] / 8;
  int E = in_sizes[2];
  int G = out_size / 64;
  const int* src = ei;
  const int* dst = ei + E;
  int nb = (N + 255) / 256;   // <=256 scan blocks (N=50000 -> 196)

  // workspace layout
  float* ws      = (float*)d_ws;
  float* h0      = ws;                          // N*64 f32
  float* B1      = h0     + (size_t)N * 64;     // N*256 f32 (xr)
  float* B2      = B1     + (size_t)N * 256;    // N*256 f32 (layer1 out)
  float* sums    = B2     + (size_t)N * 256;    // G*256
  float* cnt     = sums   + (size_t)G * 256;    // G
  unsigned short* xlb = (unsigned short*)(cnt + G);      // N*256 bf16 (16B-aligned)
  int2*  edg     = (int2*)(xlb + (size_t)N * 256);       // E (src, ea)
  int*   rowptr  = (int*)(edg + (size_t)E);              // N+1
  int*   cursor  = rowptr + (size_t)(N + 1);             // N
  int*   partial = cursor + (size_t)N;                   // nb

  // encoder
  encoder_kernel<<<(N * 64 + 255) / 256, 256, 0, stream>>>(x, enc_W, enc_b, h0, N);

  // CSR build (shared by both layers — dst is static)
  hipMemsetAsync(cursor, 0, (size_t)N * sizeof(int), stream);
  hist_kernel<<<(E + 255) / 256, 256, 0, stream>>>(dst, cursor, E);
  scan_partial_kernel<<<nb, 256, 0, stream>>>(cursor, partial, N);
  scan_offsets_kernel<<<1, 256, 0, stream>>>(partial, nb);
  scan_final_kernel<<<nb, 256, 0, stream>>>(cursor, partial, rowptr, cursor, N, E);
  scatter_build_kernel<<<(E + 255) / 256, 256, 0, stream>>>(src, dst, ea, cursor, edg, E);

  // GAT layer 1 (K=64): h0 -> B2
  lin_lr_kernel<64><<<(N + 7) / 8, 256, 0, stream>>>(h0, Wl1, bl1, Wr1, br1, xlb, B1, N);
  gat_aggregate_kernel<false><<<(N + 3) / 4, 256, 0, stream>>>(
      rowptr, edg, xlb, B1, We1, att1, bias1, B2, nullptr, nullptr, nullptr, N);

  // GAT layer 2 (K=256): B2 -> pooled sums directly
  lin_lr_kernel<256><<<(N + 7) / 8, 256, 0, stream>>>(B2, Wl2, bl2, Wr2, br2, xlb, B1, N);
  hipMemsetAsync(sums, 0, ((size_t)G * 256 + G) * sizeof(float), stream);
  gat_aggregate_kernel<true><<<(N + 3) / 4, 256, 0, stream>>>(
      rowptr, edg, xlb, B1, We2, att2, bias2, nullptr, batch, sums, cnt, N);

  // per-graph MLP
  mlp_kernel<<<G, 128, 0, stream>>>(sums, cnt, p1W, p1b, lng, lnb, p2W, p2b, outp, G);
}